// Round 6
// baseline (42001.825 us; speedup 1.0000x reference)
//
#include <hip/hip_runtime.h>

// ================= problem constants =================
#define TT 2048
#define NTHR 512
#define NWG 256        // blockIdx%8 -> XCD round-robin; actives: wg%8==0 (32 WGs on XCD0)

// ================= workspace layout (bytes) =================
#define ABORT_O 0
#define TOK_O   128      // u32[32] local-rail functional test tokens
#define VER_O   512      // u32[32] purity verdicts (deep rail)
#define FLA_O   1024     // 32 x 128B flags, local rail
#define FLB_O   5120     // 32 x 128B flags, deep rail
#define H0_O    16384    // 2 parity x 64KB: [comp2][kb32][b64][8] bf16
#define H1_O    147456   // 2 parity x 64KB
#define WS_TOTAL 278528

// ================= LDS layout (byte offsets into dynamic smem) =================
#define A0_HI   0        // L0: Whh0 slice [kb32][row64][8] bf16
#define A0_LO   32768
#define A_IH_HI 0        // L1: four 32KB weight blocks
#define A_IH_LO 32768
#define A_HH_HI 65536
#define A_HH_LO 98304
#define P_O     131072   // [64][68] f32
#define CB_O    148480   // [16][64] f32 c-state
#define BIAS_O  152576   // [64] f32
#define WIB_O   152832   // [64] f32 (L0 only)
#define XB_O    153088   // [64] f32 (L0 only)
#define FWL_O   152832   // [16] f32 (L1 only; aliases WIB region)
#define SMEM_BYTES 153344

typedef __bf16 bf16;
typedef __bf16 bf16x8 __attribute__((ext_vector_type(8)));
typedef float f32x4 __attribute__((ext_vector_type(4)));
typedef unsigned int u32;
typedef u32 u32x4 __attribute__((ext_vector_type(4)));
typedef unsigned short u16;

__device__ __forceinline__ f32x4 MFMA(bf16x8 a, bf16x8 b, f32x4 c) {
  return __builtin_amdgcn_mfma_f32_16x16x32_bf16(a, b, c, 0, 0, 0);
}
__device__ __forceinline__ float sigf(float v) { return 1.0f / (1.0f + __expf(-v)); }
__device__ __forceinline__ float tanhfast(float x) {
  float e = __expf(2.0f * x);          // inf/0 saturate correctly to +-1
  return 1.0f - 2.0f / (e + 1.0f);
}
__device__ __forceinline__ u16 bfbits(float f) { return __builtin_bit_cast(u16, (bf16)f); }
__device__ __forceinline__ u32 pack2(float a, float b) {
  return ((u32)bfbits(b) << 16) | bfbits(a);
}

// ---------- transport primitives ----------
// local rail: plain store (write-through to this XCD's L2) + sc0 load (L1-bypass).
// deep rail : sc0 sc1 store/load at the Infinity Cache — device-coherent (R3/R5-proven).
__device__ __forceinline__ bf16x8 ld16x(const void* p, bool pure) {
  u32x4 v;
  if (pure) asm volatile("global_load_dwordx4 %0, %1, off sc0"     : "=v"(v) : "v"(p));
  else      asm volatile("global_load_dwordx4 %0, %1, off sc0 sc1" : "=v"(v) : "v"(p));
  return __builtin_bit_cast(bf16x8, v);
}
__device__ __forceinline__ void wait_all_loads() {
  asm volatile("s_waitcnt vmcnt(0)" ::: "memory");
  __builtin_amdgcn_sched_barrier(0);
}
__device__ __forceinline__ void st32x(u32* p, u32 v, bool pure) {
  if (pure) asm volatile("global_store_dword %0, %1, off"          :: "v"(p), "v"(v) : "memory");
  else      asm volatile("global_store_dword %0, %1, off sc0 sc1"  :: "v"(p), "v"(v) : "memory");
}
__device__ __forceinline__ void st32_deep(u32* p, u32 v) {
  asm volatile("global_store_dword %0, %1, off sc0 sc1" :: "v"(p), "v"(v) : "memory");
}
__device__ __forceinline__ void st32_plain(u32* p, u32 v) {
  asm volatile("global_store_dword %0, %1, off" :: "v"(p), "v"(v) : "memory");
}
__device__ __forceinline__ u32 ld_sc0(const u32* p) {
  u32 v;
  asm volatile("global_load_dword %0, %1, off sc0\n\ts_waitcnt vmcnt(0)"
               : "=v"(v) : "v"(p) : "memory");
  return v;
}
__device__ __forceinline__ u32 ld_deep(const u32* p) {
  u32 v;
  asm volatile("global_load_dword %0, %1, off sc0 sc1\n\ts_waitcnt vmcnt(0)"
               : "=v"(v) : "v"(p) : "memory");
  return v;
}

// bounded single-domain barrier wait: lanes poll flag[lane&31] on the fast rail;
// deep-rail safety check every 32 iters; abort check every 128; hard bound -> abort.
__device__ __forceinline__ void wait_flags(const u32* fA, const u32* fB, u32 need,
                                           u32* abortp, bool pure) {
  const int lane = threadIdx.x & 63;
  const u32* pA = fA + (lane & 31) * 32;
  const u32* pB = fB + (lane & 31) * 32;
  int it = 0;
  for (;;) {
    u32 v = pure ? ld_sc0(pA) : ld_deep(pB);
    if (__all((int)(v >= need))) break;
    ++it;
    if (pure && (it & 31) == 0) {
      u32 vb = ld_deep(pB);                 // deep rail is authoritative
      if (__all((int)(vb >= need))) break;
    }
    if ((it & 127) == 0) {
      u32 ab = ld_deep(abortp);
      if (__any((int)(ab != 0))) break;
      if (it >= (1 << 17)) { if (lane == 0) st32_deep(abortp, 1u); break; }
    }
  }
}

extern "C" __global__ __launch_bounds__(NTHR)
void lstm_persist(const float* __restrict__ x,
                  const float* __restrict__ Wih0, const float* __restrict__ Whh0,
                  const float* __restrict__ bih0, const float* __restrict__ bhh0,
                  const float* __restrict__ Wih1, const float* __restrict__ Whh1,
                  const float* __restrict__ bih1, const float* __restrict__ bhh1,
                  const float* __restrict__ fcw, const float* __restrict__ fcb,
                  float* __restrict__ out, char* __restrict__ ws)
{
  extern __shared__ char smem[];
  const int tid = threadIdx.x;
  const int wg  = blockIdx.x;
  if (wg & 7) return;                  // keep only XCD0's round-robin slots
  const int slot = wg >> 3;            // 0..31
  const bool isL1 = slot >= 16;
  const int sl = isL1 ? slot - 16 : slot;   // dim-group 0..15 within role

  u32* abortp = (u32*)(ws + ABORT_O);
  u32* tok    = (u32*)(ws + TOK_O);
  u32* ver    = (u32*)(ws + VER_O);
  u32* fA     = (u32*)(ws + FLA_O);
  u32* fB     = (u32*)(ws + FLB_O);

  // ---- purity: FUNCTIONAL local-rail test, then unanimous deep-rail verdict ----
  __shared__ u32 pure_sh;
  if (tid == 0) st32_plain(&tok[slot], 1u);      // local-rail token
  if (tid < 64) {
    const u32* pp = tok + (tid & 31);
    u32 myver = 0;
    for (int it = 0; it < (1 << 15); ++it) {
      u32 v = ld_sc0(pp);
      if (__all((int)(v != 0))) { myver = 1; break; }
    }
    if (tid == 0) st32_deep(&ver[slot], myver + 1u);   // 1=impure, 2=pure
    // gather all verdicts over the reliable deep rail
    const u32* vp = ver + (tid & 31);
    u32 vv = 0;
    for (int it = 0; it < (1 << 17); ++it) {
      vv = ld_deep(vp);
      if (__all((int)(vv != 0))) break;
    }
    int allpure = __all((int)(vv == 2u));
    if (tid == 0) pure_sh = (u32)allpure;
  }
  __syncthreads();
  const bool pure = (pure_sh != 0);

  const int w = tid >> 6, l = tid & 63, lr = l & 15, lk = l >> 4;
  const int rowb = (w & 1) * 32, colb = (w >> 1) * 16;

  float* P    = (float*)(smem + P_O);
  float* cbuf = (float*)(smem + CB_O);
  float* bias = (float*)(smem + BIAS_O);

  // ---- one-time weight staging (split-bf16 k-panel fragments; R5-proven layout) ----
  if (!isL1) {
    bf16x8* Ahi = (bf16x8*)(smem + A0_HI);
    bf16x8* Alo = (bf16x8*)(smem + A0_LO);
    float* wib  = (float*)(smem + WIB_O);
    for (int i = tid; i < 2048; i += NTHR) {     // i = row*32 + kb
      int row = i >> 5, kb = i & 31;
      int grow = (row >> 4) * 256 + sl * 16 + (row & 15);
      const float* src = Whh0 + grow * 256 + kb * 8;
      bf16x8 hi, lo;
#pragma unroll
      for (int e = 0; e < 8; e++) { float v = src[e]; bf16 h = (bf16)v; hi[e] = h; lo[e] = (bf16)(v - (float)h); }
      Ahi[kb * 64 + row] = hi;  Alo[kb * 64 + row] = lo;
    }
    if (tid < 64) {
      int grow = (tid >> 4) * 256 + sl * 16 + (tid & 15);
      wib[tid]  = Wih0[grow];
      bias[tid] = bih0[grow] + bhh0[grow];
    }
  } else {
    bf16x8* AihH = (bf16x8*)(smem + A_IH_HI);
    bf16x8* AihL = (bf16x8*)(smem + A_IH_LO);
    bf16x8* AhhH = (bf16x8*)(smem + A_HH_HI);
    bf16x8* AhhL = (bf16x8*)(smem + A_HH_LO);
    float* fwl   = (float*)(smem + FWL_O);
    for (int i = tid; i < 2048; i += NTHR) {
      int row = i >> 5, kb = i & 31;
      int grow = (row >> 4) * 256 + sl * 16 + (row & 15);
      {
        const float* src = Wih1 + grow * 256 + kb * 8;
        bf16x8 hi, lo;
#pragma unroll
        for (int e = 0; e < 8; e++) { float v = src[e]; bf16 h = (bf16)v; hi[e] = h; lo[e] = (bf16)(v - (float)h); }
        AihH[kb * 64 + row] = hi;  AihL[kb * 64 + row] = lo;
      }
      {
        const float* src = Whh1 + grow * 256 + kb * 8;
        bf16x8 hi, lo;
#pragma unroll
        for (int e = 0; e < 8; e++) { float v = src[e]; bf16 h = (bf16)v; hi[e] = h; lo[e] = (bf16)(v - (float)h); }
        AhhH[kb * 64 + row] = hi;  AhhL[kb * 64 + row] = lo;
      }
    }
    if (tid < 64) {
      int grow = (tid >> 4) * 256 + sl * 16 + (tid & 15);
      bias[tid] = bih1[grow] + bhh1[grow];
    }
    if (tid < 16) fwl[tid] = fcw[sl * 16 + tid];
  }
  for (int i = tid; i < 1024; i += NTHR) cbuf[i] = 0.0f;
  __syncthreads();

  const float fb = fcb[0];

  // ================= superstep loop: L0 computes h0[t], L1 computes h1[t-1] =================
  for (int t = 0; t <= TT; ++t) {
    if (t > 0) {
      if (tid < 64) wait_flags(fA, fB, (u32)t, abortp, pure);
      __syncthreads();
    }

    if (!isL1) {
      if (t < TT) {
        float* wib = (float*)(smem + WIB_O);
        float* xb  = (float*)(smem + XB_O);
        const char* hp = ws + H0_O + (size_t)((t - 1) & 1) * 65536;
        bf16x8 bh[8], bl[8];
#pragma unroll
        for (int ks = 0; ks < 8; ks++) {
          int kb = ks * 4 + lk;
          const char* p = hp + (size_t)(kb * 64 + colb + lr) * 16;
          bh[ks] = ld16x(p, pure);
          bl[ks] = ld16x(p + 32768, pure);
        }
        if (tid < 64) xb[tid] = x[(size_t)tid * TT + t];
        wait_all_loads();

        bf16x8* Ahi = (bf16x8*)(smem + A0_HI);
        bf16x8* Alo = (bf16x8*)(smem + A0_LO);
        f32x4 acc0 = {0.f,0.f,0.f,0.f}, acc1 = {0.f,0.f,0.f,0.f};
#pragma unroll
        for (int ks = 0; ks < 8; ks++) {
          int kb = ks * 4 + lk;
          bf16x8 a0h = Ahi[kb * 64 + rowb + lr], a1h = Ahi[kb * 64 + rowb + 16 + lr];
          bf16x8 a0l = Alo[kb * 64 + rowb + lr], a1l = Alo[kb * 64 + rowb + 16 + lr];
          acc0 = MFMA(a0h, bh[ks], acc0);  acc1 = MFMA(a1h, bh[ks], acc1);
          acc0 = MFMA(a0h, bl[ks], acc0);  acc1 = MFMA(a1h, bl[ks], acc1);
          acc0 = MFMA(a0l, bh[ks], acc0);  acc1 = MFMA(a1l, bh[ks], acc1);
        }
#pragma unroll
        for (int r = 0; r < 4; r++) {
          P[(rowb + lk * 4 + r) * 68 + colb + lr]      = acc0[r];
          P[(rowb + 16 + lk * 4 + r) * 68 + colb + lr] = acc1[r];
        }
        __syncthreads();

        // gates -> h0[t] into parity buffer (local rail when pure)
        {
          u32* eh = (u32*)(ws + H0_O + (size_t)(t & 1) * 65536);
          u32* el = (u32*)((char*)eh + 32768);
          int b = tid >> 3, p = tid & 7;
          float xv = xb[b];
          float hv[2], rv[2];
#pragma unroll
          for (int q = 0; q < 2; q++) {
            int d = p * 2 + q;
            float pi = P[(d) * 68 + b]      + wib[d] * xv      + bias[d];
            float pf = P[(16 + d) * 68 + b] + wib[16 + d] * xv + bias[16 + d];
            float pg = P[(32 + d) * 68 + b] + wib[32 + d] * xv + bias[32 + d];
            float po = P[(48 + d) * 68 + b] + wib[48 + d] * xv + bias[48 + d];
            float c = sigf(pf) * cbuf[d * 64 + b] + sigf(pi) * tanhfast(pg);
            cbuf[d * 64 + b] = c;
            float h = sigf(po) * tanhfast(c);
            hv[q] = h;  rv[q] = h - (float)((bf16)h);
          }
          int kbg = sl * 2 + (p >> 2);
          u32 wi = (u32)((kbg * 64 + b) * 4 + (p & 3));
          st32x(eh + wi, pack2(hv[0], hv[1]), pure);
          st32x(el + wi, pack2(rv[0], rv[1]), pure);
        }
      }
    } else {
      if (t >= 1) {
        const char* h0p = ws + H0_O + (size_t)((t - 1) & 1) * 65536;  // h0[t-1]
        const char* h1p = ws + H1_O + (size_t)(t & 1) * 65536;        // h1[t-2]
        bf16x8 b0h[8], b0l[8], b1h[8], b1l[8];
#pragma unroll
        for (int ks = 0; ks < 8; ks++) {
          int kb = ks * 4 + lk;
          const char* p0 = h0p + (size_t)(kb * 64 + colb + lr) * 16;
          const char* p1 = h1p + (size_t)(kb * 64 + colb + lr) * 16;
          b0h[ks] = ld16x(p0, pure);  b0l[ks] = ld16x(p0 + 32768, pure);
          b1h[ks] = ld16x(p1, pure);  b1l[ks] = ld16x(p1 + 32768, pure);
        }
        wait_all_loads();

        bf16x8* AihH = (bf16x8*)(smem + A_IH_HI);
        bf16x8* AihL = (bf16x8*)(smem + A_IH_LO);
        bf16x8* AhhH = (bf16x8*)(smem + A_HH_HI);
        bf16x8* AhhL = (bf16x8*)(smem + A_HH_LO);
        f32x4 acc0 = {0.f,0.f,0.f,0.f}, acc1 = {0.f,0.f,0.f,0.f};
#pragma unroll
        for (int ks = 0; ks < 8; ks++) {
          int kb = ks * 4 + lk;
          bf16x8 aih0 = AihH[kb * 64 + rowb + lr], aih1 = AihH[kb * 64 + rowb + 16 + lr];
          bf16x8 ail0 = AihL[kb * 64 + rowb + lr], ail1 = AihL[kb * 64 + rowb + 16 + lr];
          acc0 = MFMA(aih0, b0h[ks], acc0);  acc1 = MFMA(aih1, b0h[ks], acc1);
          acc0 = MFMA(aih0, b0l[ks], acc0);  acc1 = MFMA(aih1, b0l[ks], acc1);
          acc0 = MFMA(ail0, b0h[ks], acc0);  acc1 = MFMA(ail1, b0h[ks], acc1);
          bf16x8 ahh0 = AhhH[kb * 64 + rowb + lr], ahh1 = AhhH[kb * 64 + rowb + 16 + lr];
          bf16x8 ahl0 = AhhL[kb * 64 + rowb + lr], ahl1 = AhhL[kb * 64 + rowb + 16 + lr];
          acc0 = MFMA(ahh0, b1h[ks], acc0);  acc1 = MFMA(ahh1, b1h[ks], acc1);
          acc0 = MFMA(ahh0, b1l[ks], acc0);  acc1 = MFMA(ahh1, b1l[ks], acc1);
          acc0 = MFMA(ahl0, b1h[ks], acc0);  acc1 = MFMA(ahl1, b1h[ks], acc1);
        }
#pragma unroll
        for (int r = 0; r < 4; r++) {
          P[(rowb + lk * 4 + r) * 68 + colb + lr]      = acc0[r];
          P[(rowb + 16 + lk * 4 + r) * 68 + colb + lr] = acc1[r];
        }
        __syncthreads();

        // gates -> h1[t-1]; stash f32 h into P rows 0-15 for the inlined FC
        {
          u32* rh = (u32*)(ws + H1_O + (size_t)((t - 1) & 1) * 65536);
          u32* rl = (u32*)((char*)rh + 32768);
          int b = tid >> 3, p = tid & 7;
          float hv[2], rv[2];
#pragma unroll
          for (int q = 0; q < 2; q++) {
            int d = p * 2 + q;
            float pi = P[(d) * 68 + b]      + bias[d];
            float pf = P[(16 + d) * 68 + b] + bias[16 + d];
            float pg = P[(32 + d) * 68 + b] + bias[32 + d];
            float po = P[(48 + d) * 68 + b] + bias[48 + d];
            float c = sigf(pf) * cbuf[d * 64 + b] + sigf(pi) * tanhfast(pg);
            cbuf[d * 64 + b] = c;
            float h = sigf(po) * tanhfast(c);
            hv[q] = h;  rv[q] = h - (float)((bf16)h);
            P[d * 68 + b] = h;          // own cell: read-then-write by same thread only
          }
          int kbg = sl * 2 + (p >> 2);
          u32 wi = (u32)((kbg * 64 + b) * 4 + (p & 3));
          st32x(rh + wi, pack2(hv[0], hv[1]), pure);
          st32x(rl + wi, pack2(rv[0], rv[1]), pure);
        }
      }
    }

    // drain data stores (plain acks are local-L2 fast), then post dual-rail flag
    asm volatile("s_waitcnt vmcnt(0)" ::: "memory");
    __syncthreads();
    if (tid == 0 && t < TT) {
      st32_plain(fA + slot * 32, (u32)(t + 1));
      st32_deep (fB + slot * 32, (u32)(t + 1));
    }
    // inlined FC (off critical path, after flag post)
    if (isL1 && t >= 1 && tid < 64) {
      float* fwl = (float*)(smem + FWL_O);
      float acc = 0.0f;
#pragma unroll
      for (int d = 0; d < 16; d++) acc += fwl[d] * P[d * 68 + tid];
      if (sl == 0) acc += fb;
      atomicAdd(out + (size_t)tid * TT + (t - 1), acc);
    }
  }
}

extern "C" void kernel_launch(void* const* d_in, const int* in_sizes, int n_in,
                              void* d_out, int out_size, void* d_ws, size_t ws_size,
                              hipStream_t stream) {
  (void)in_sizes; (void)n_in; (void)ws_size;
  hipFuncSetAttribute((const void*)lstm_persist,
                      hipFuncAttributeMaxDynamicSharedMemorySize, SMEM_BYTES);
  hipMemsetAsync(d_ws, 0, WS_TOTAL, stream);                           // flags/tokens/h-state
  hipMemsetAsync(d_out, 0, (size_t)out_size * sizeof(float), stream);  // FC accumulates
  lstm_persist<<<dim3(NWG), dim3(NTHR), SMEM_BYTES, stream>>>(
      (const float*)d_in[0],
      (const float*)d_in[1], (const float*)d_in[2],
      (const float*)d_in[3], (const float*)d_in[4],
      (const float*)d_in[5], (const float*)d_in[6],
      (const float*)d_in[7], (const float*)d_in[8],
      (const float*)d_in[9], (const float*)d_in[10],
      (float*)d_out, (char*)d_ws);
}

// Round 7
// 9151.987 us; speedup vs baseline: 4.5894x; 4.5894x over previous
//
#include <hip/hip_runtime.h>

// ================= problem constants =================
#define TT 2048
#define NTHR 512
#define NWG 64           // 32 L0 WGs + 32 L1 WGs; 8 h-dims each; all 64 batches

// ================= workspace layout (bytes) =================
#define ABORT_O 0
#define FL_O    1024     // 64 x 128B flags (deep rail)
#define H0_O    16384    // 2 parity x 64KB: hi[256d x 64b] bf16 (32KB) + lo (32KB)
#define H1_O    (16384 + 2*65536)
#define WS_TOTAL (16384 + 4*65536)

// ================= LDS layout (byte offsets into dynamic smem) =================
// weight rows INTERLEAVED: LDS row r (0..31) = gate (r&3) of local dim (r>>2)
#define A0_HI    0       // L0: Whh0 slice [kb32][row32][8] bf16 (16KB)
#define A0_LO    16384
#define AIH_HI   0       // L1: Wih1 slice
#define AIH_LO   16384
#define AHH_HI   32768   // L1: Whh1 slice
#define AHH_LO   49152
#define FWL_O    65536   // [8] f32 (L1)
#define HSH_O    65600   // [8][64] f32 h-stash for FC (L1)
#define SMEM_BYTES 67648

typedef __bf16 bf16;
typedef __bf16 bf16x8 __attribute__((ext_vector_type(8)));
typedef float f32x4 __attribute__((ext_vector_type(4)));
typedef unsigned int u32;
typedef u32 u32x4 __attribute__((ext_vector_type(4)));
typedef unsigned short u16;

__device__ __forceinline__ f32x4 MFMA(bf16x8 a, bf16x8 b, f32x4 c) {
  return __builtin_amdgcn_mfma_f32_16x16x32_bf16(a, b, c, 0, 0, 0);
}
__device__ __forceinline__ float sigf(float v) { return 1.0f / (1.0f + __expf(-v)); }
__device__ __forceinline__ float tanhfast(float x) {
  float e = __expf(2.0f * x);
  return 1.0f - 2.0f / (e + 1.0f);
}
__device__ __forceinline__ u16 bfbits(float f) { return __builtin_bit_cast(u16, (bf16)f); }

// ---------- deep-rail transport (sc0 sc1 -> Infinity Cache; device-coherent, R3/R5-proven) ----------
__device__ __forceinline__ bf16x8 ld16d(const void* p) {
  u32x4 v;
  asm volatile("global_load_dwordx4 %0, %1, off sc0 sc1" : "=v"(v) : "v"(p));
  return __builtin_bit_cast(bf16x8, v);
}
__device__ __forceinline__ void wait_all_loads() {
  asm volatile("s_waitcnt vmcnt(0)" ::: "memory");
  __builtin_amdgcn_sched_barrier(0);
}
__device__ __forceinline__ void st16d(void* p, u16 h) {
  u32 v = h;
  asm volatile("global_store_short %0, %1, off sc0 sc1" :: "v"(p), "v"(v) : "memory");
}
__device__ __forceinline__ void st32_deep(u32* p, u32 v) {
  asm volatile("global_store_dword %0, %1, off sc0 sc1" :: "v"(p), "v"(v) : "memory");
}
__device__ __forceinline__ u32 ld_deep(const u32* p) {
  u32 v;
  asm volatile("global_load_dword %0, %1, off sc0 sc1\n\ts_waitcnt vmcnt(0)"
               : "=v"(v) : "v"(p) : "memory");
  return v;
}

// bounded lockstep barrier wait (wave0 only): lane l polls flags[l]; abort -> bail fast.
__device__ __forceinline__ void wait_barrier(const u32* flags, u32 need, u32* abortp) {
  const int lane = threadIdx.x & 63;
  const u32* p = flags + lane * 32;          // 128B-padded flag lines
  int it = 0;
  for (;;) {
    u32 v = ld_deep(p);
    if (__all((int)(v >= need))) break;
    if (((++it) & 63) == 0) {
      u32 ab = ld_deep(abortp);
      if (__any((int)(ab != 0))) break;
      if (it >= (1 << 16)) { if (lane == 0) st32_deep(abortp, 1u); break; }
    }
  }
}

extern "C" __global__ __launch_bounds__(NTHR)
void lstm_persist(const float* __restrict__ x,
                  const float* __restrict__ Wih0, const float* __restrict__ Whh0,
                  const float* __restrict__ bih0, const float* __restrict__ bhh0,
                  const float* __restrict__ Wih1, const float* __restrict__ Whh1,
                  const float* __restrict__ bih1, const float* __restrict__ bhh1,
                  const float* __restrict__ fcw, const float* __restrict__ fcb,
                  float* __restrict__ out, char* __restrict__ ws)
{
  extern __shared__ char smem[];
  const int tid  = threadIdx.x;
  const int slot = blockIdx.x;         // 0..63
  const bool isL1 = slot >= 32;
  const int sl = isL1 ? slot - 32 : slot;   // dim-group: dims [sl*8, sl*8+8)

  u32* abortp = (u32*)(ws + ABORT_O);
  u32* flags  = (u32*)(ws + FL_O);

  const int w = tid >> 6, l = tid & 63, lr = l & 15, lk = l >> 4;
  const int rowb = (w & 1) * 16;       // output row-tile (of 32 rows = 8 dims x 4 gates)
  const int colb = (w >> 1) * 16;      // batch-tile
  const int b  = colb + lr;            // this lane's batch
  const int i  = (w & 1) * 4 + lk;     // this lane's local dim (0..7)
  const int gd = sl * 8 + i;           // global dim

  // ---------- one-time staging: interleaved weight rows (LDS row r = gate(r&3), dim(r>>2)) ----------
  if (!isL1) {
    bf16x8* Ahi = (bf16x8*)(smem + A0_HI);
    bf16x8* Alo = (bf16x8*)(smem + A0_LO);
    for (int idx = tid; idx < 1024; idx += NTHR) {   // idx = r*32 + kb
      int r = idx >> 5, kb = idx & 31;
      int grow = (r & 3) * 256 + sl * 8 + (r >> 2);
      const float* src = Whh0 + grow * 256 + kb * 8;
      bf16x8 hi, lo;
#pragma unroll
      for (int e = 0; e < 8; e++) { float v = src[e]; bf16 h = (bf16)v; hi[e] = h; lo[e] = (bf16)(v - (float)h); }
      Ahi[kb * 32 + r] = hi;  Alo[kb * 32 + r] = lo;
    }
  } else {
    bf16x8* AihH = (bf16x8*)(smem + AIH_HI);
    bf16x8* AihL = (bf16x8*)(smem + AIH_LO);
    bf16x8* AhhH = (bf16x8*)(smem + AHH_HI);
    bf16x8* AhhL = (bf16x8*)(smem + AHH_LO);
    for (int idx = tid; idx < 1024; idx += NTHR) {
      int r = idx >> 5, kb = idx & 31;
      int grow = (r & 3) * 256 + sl * 8 + (r >> 2);
      {
        const float* src = Wih1 + grow * 256 + kb * 8;
        bf16x8 hi, lo;
#pragma unroll
        for (int e = 0; e < 8; e++) { float v = src[e]; bf16 h = (bf16)v; hi[e] = h; lo[e] = (bf16)(v - (float)h); }
        AihH[kb * 32 + r] = hi;  AihL[kb * 32 + r] = lo;
      }
      {
        const float* src = Whh1 + grow * 256 + kb * 8;
        bf16x8 hi, lo;
#pragma unroll
        for (int e = 0; e < 8; e++) { float v = src[e]; bf16 h = (bf16)v; hi[e] = h; lo[e] = (bf16)(v - (float)h); }
        AhhH[kb * 32 + r] = hi;  AhhL[kb * 32 + r] = lo;
      }
    }
    if (tid < 8) ((float*)(smem + FWL_O))[tid] = fcw[sl * 8 + tid];
  }

  // per-lane gate constants in VGPRs
  float wib_r[4], bias_r[4];
#pragma unroll
  for (int g = 0; g < 4; g++) {
    if (!isL1) { wib_r[g] = Wih0[g * 256 + gd]; bias_r[g] = bih0[g * 256 + gd] + bhh0[g * 256 + gd]; }
    else       { wib_r[g] = 0.0f;               bias_r[g] = bih1[g * 256 + gd] + bhh1[g * 256 + gd]; }
  }
  float creg = 0.0f;                   // per-lane c-state (dim i, batch b) — fixed across steps
  const float fb = fcb[0];
  __syncthreads();

  // ================= superstep loop: L0 computes h0[t], L1 computes h1[t-1] =================
  for (int t = 0; t <= TT; ++t) {
    if (t > 0) {
      if (tid < 64) wait_barrier(flags, (u32)t, abortp);
      __syncthreads();
    }

    if (!isL1) {
      if (t < TT) {
        const char* hp = ws + H0_O + (size_t)((t - 1) & 1) * 65536;   // h0[t-1]
        bf16x8 bh[8], bl[8];
#pragma unroll
        for (int ks = 0; ks < 8; ks++) {
          int kb = ks * 4 + lk;
          const char* p = hp + (size_t)(kb * 64 + b) * 16;
          bh[ks] = ld16d(p);
          bl[ks] = ld16d(p + 32768);
        }
        float xv = x[(size_t)b * TT + t];       // cached plain load (same 64 vals for all L0 WGs)
        wait_all_loads();

        bf16x8* Ahi = (bf16x8*)(smem + A0_HI);
        bf16x8* Alo = (bf16x8*)(smem + A0_LO);
        f32x4 acc = {0.f, 0.f, 0.f, 0.f};
#pragma unroll
        for (int ks = 0; ks < 8; ks++) {
          int kb = ks * 4 + lk;
          bf16x8 ah = Ahi[kb * 32 + rowb + lr];
          bf16x8 al = Alo[kb * 32 + rowb + lr];
          acc = MFMA(ah, bh[ks], acc);
          acc = MFMA(ah, bl[ks], acc);
          acc = MFMA(al, bh[ks], acc);
        }
        // in-register gates: acc[r] = gate r of (dim i, batch b)
        float pi = acc[0] + wib_r[0] * xv + bias_r[0];
        float pf = acc[1] + wib_r[1] * xv + bias_r[1];
        float pg = acc[2] + wib_r[2] * xv + bias_r[2];
        float po = acc[3] + wib_r[3] * xv + bias_r[3];
        float c = sigf(pf) * creg + sigf(pi) * tanhfast(pg);
        creg = c;
        float h = sigf(po) * tanhfast(c);
        u16 hb = bfbits(h);
        u16 lb = bfbits(h - (float)(bf16)h);
        char* wp = ws + H0_O + (size_t)(t & 1) * 65536 + (size_t)(sl * 64 + b) * 16 + i * 2;
        st16d(wp, hb);
        st16d(wp + 32768, lb);
      }
    } else {
      if (t >= 1) {
        const char* h0p = ws + H0_O + (size_t)((t - 1) & 1) * 65536;  // h0[t-1]
        const char* h1p = ws + H1_O + (size_t)(t & 1) * 65536;        // h1[t-2]
        bf16x8 b0h[8], b0l[8], b1h[8], b1l[8];
#pragma unroll
        for (int ks = 0; ks < 8; ks++) {
          int kb = ks * 4 + lk;
          const char* p0 = h0p + (size_t)(kb * 64 + b) * 16;
          const char* p1 = h1p + (size_t)(kb * 64 + b) * 16;
          b0h[ks] = ld16d(p0);  b0l[ks] = ld16d(p0 + 32768);
          b1h[ks] = ld16d(p1);  b1l[ks] = ld16d(p1 + 32768);
        }
        wait_all_loads();

        bf16x8* AihH = (bf16x8*)(smem + AIH_HI);
        bf16x8* AihL = (bf16x8*)(smem + AIH_LO);
        bf16x8* AhhH = (bf16x8*)(smem + AHH_HI);
        bf16x8* AhhL = (bf16x8*)(smem + AHH_LO);
        f32x4 acc = {0.f, 0.f, 0.f, 0.f};
#pragma unroll
        for (int ks = 0; ks < 8; ks++) {
          int kb = ks * 4 + lk;
          bf16x8 aih = AihH[kb * 32 + rowb + lr];
          bf16x8 ail = AihL[kb * 32 + rowb + lr];
          bf16x8 ahh = AhhH[kb * 32 + rowb + lr];
          bf16x8 ahl = AhhL[kb * 32 + rowb + lr];
          acc = MFMA(aih, b0h[ks], acc);
          acc = MFMA(aih, b0l[ks], acc);
          acc = MFMA(ail, b0h[ks], acc);
          acc = MFMA(ahh, b1h[ks], acc);
          acc = MFMA(ahh, b1l[ks], acc);
          acc = MFMA(ahl, b1h[ks], acc);
        }
        float pi = acc[0] + bias_r[0];
        float pf = acc[1] + bias_r[1];
        float pg = acc[2] + bias_r[2];
        float po = acc[3] + bias_r[3];
        float c = sigf(pf) * creg + sigf(pi) * tanhfast(pg);
        creg = c;
        float h = sigf(po) * tanhfast(c);
        u16 hb = bfbits(h);
        u16 lb = bfbits(h - (float)(bf16)h);
        char* wp = ws + H1_O + (size_t)((t - 1) & 1) * 65536 + (size_t)(sl * 64 + b) * 16 + i * 2;
        st16d(wp, hb);
        st16d(wp + 32768, lb);
        ((float*)(smem + HSH_O))[i * 64 + b] = h;    // stash for inlined FC
      }
    }

    // drain deep stores, then post flag (single lockstep barrier value t+1)
    asm volatile("s_waitcnt vmcnt(0)" ::: "memory");
    __syncthreads();
    if (tid == 0 && t < TT)
      st32_deep(flags + slot * 32, (u32)(t + 1));

    // inlined FC on wave1 (off the polling wave, off the critical path)
    if (isL1 && t >= 1 && tid >= 64 && tid < 128) {
      const float* hsh = (const float*)(smem + HSH_O);
      const float* fwl = (const float*)(smem + FWL_O);
      int bb = tid - 64;
      float acc = 0.0f;
#pragma unroll
      for (int d = 0; d < 8; d++) acc += fwl[d] * hsh[d * 64 + bb];
      if (sl == 0) acc += fb;
      atomicAdd(out + (size_t)bb * TT + (t - 1), acc);
    }
  }
}

extern "C" void kernel_launch(void* const* d_in, const int* in_sizes, int n_in,
                              void* d_out, int out_size, void* d_ws, size_t ws_size,
                              hipStream_t stream) {
  (void)in_sizes; (void)n_in; (void)ws_size;
  hipFuncSetAttribute((const void*)lstm_persist,
                      hipFuncAttributeMaxDynamicSharedMemorySize, SMEM_BYTES);
  hipMemsetAsync(d_ws, 0, WS_TOTAL, stream);                           // flags + zero h-state
  hipMemsetAsync(d_out, 0, (size_t)out_size * sizeof(float), stream);  // FC accumulates
  lstm_persist<<<dim3(NWG), dim3(NTHR), SMEM_BYTES, stream>>>(
      (const float*)d_in[0],
      (const float*)d_in[1], (const float*)d_in[2],
      (const float*)d_in[3], (const float*)d_in[4],
      (const float*)d_in[5], (const float*)d_in[6],
      (const float*)d_in[7], (const float*)d_in[8],
      (const float*)d_in[9], (const float*)d_in[10],
      (float*)d_out, (char*)d_ws);
}